// Round 1
// 185.949 us; speedup vs baseline: 1.0638x; 1.0638x over previous
//
#include <hip/hip_runtime.h>
#include <math.h>

#define N_NODES 50000
#define N_EDGES 800000
#define NPART 8
#define PART_SZ ((N_NODES + NPART - 1) / NPART)   // 6250
#define CAP 64                                    // per-node bucket capacity
#define SCAT_BLOCKS 4096                          // 8 parts x 512 blocks
#define FC_BLOCKS 784                             // ceil(3125/4)=782, padded to x8

typedef __attribute__((ext_vector_type(8))) short short8;
typedef __attribute__((ext_vector_type(8))) unsigned short ushort8;
typedef __attribute__((ext_vector_type(4))) float v4f;
typedef __attribute__((ext_vector_type(2))) float v2f;
typedef __attribute__((ext_vector_type(4))) int int4v;

// ---- bf16 helpers (raw ushort storage) ----
__device__ __forceinline__ float bf2f(unsigned short h) {
    return __uint_as_float(((unsigned int)h) << 16);
}
__device__ __forceinline__ unsigned short f2bf(float f) {
    unsigned int u = __float_as_uint(f);
    u += 0x7fff + ((u >> 16) & 1);          // round-to-nearest-even
    return (unsigned short)(u >> 16);
}

// A-fragment load: lane supplies row m, k = kc*32 + quad*8 + j (j=0..7)
__device__ __forceinline__ short8 load_afrag(const float* X, size_t row, int K,
                                             int kc, int quad) {
    const float* p = X + row * K + kc * 32 + quad * 8;
    const float4 t0 = *(const float4*)p;
    const float4 t1 = *(const float4*)(p + 4);
    short8 a;
    a[0] = (short)f2bf(t0.x); a[1] = (short)f2bf(t0.y);
    a[2] = (short)f2bf(t0.z); a[3] = (short)f2bf(t0.w);
    a[4] = (short)f2bf(t1.x); a[5] = (short)f2bf(t1.y);
    a[6] = (short)f2bf(t1.z); a[7] = (short)f2bf(t1.w);
    return a;
}
__device__ __forceinline__ short8 load_afrag(const unsigned short* X, size_t row,
                                             int K, int kc, int quad) {
    return *(const short8*)(X + row * K + kc * 32 + quad * 8);  // already bf16
}

// ---------------------------------------------------------------------------
// MFMA fc + attention-coefficient body. W staged into LDS as bf16 (converted
// once by the 256-thread stage loop; waves then ds_read short8 directly --
// removes the per-wave redundant f2bf repack of the old f32-LDS scheme and
// halves LDS to 17.4KB so the fused launch isn't LDS-limited).
// ---------------------------------------------------------------------------
template <int K, typename XT>
__device__ __forceinline__ void fc_att_body(
    const XT* __restrict__ X, const float* __restrict__ W,
    const float* __restrict__ al, const float* __restrict__ ar,
    unsigned short* __restrict__ Hout, float* __restrict__ el,
    float* __restrict__ er, int nTiles, int blk, unsigned short* Wlds)
{
    constexpr int KP = K + 8;                 // row pitch (u16): keeps 16B align
    constexpr int NKC = K / 32;
    const int tid = threadIdx.x;
    for (int i = tid; i < 64 * K; i += 256) {
        const int r = i / K, c = i - r * K;
        Wlds[r * KP + c] = f2bf(W[i]);
    }
    __syncthreads();

    const int lane = tid & 63;
    const int wave = tid >> 6;
    const int d = lane & 15;
    const int quad = lane >> 4;

    const int tile = blk * 4 + wave;
    if (tile >= nTiles) return;
    const int node0 = tile * 16;

    short8 wf[4][NKC];
#pragma unroll
    for (int ng = 0; ng < 4; ++ng) {
#pragma unroll
        for (int kc = 0; kc < NKC; ++kc) {
            wf[ng][kc] = *(const short8*)&Wlds[(ng * 16 + d) * KP + kc * 32 + quad * 8];
        }
    }

    v4f cc[4] = {{0.f,0.f,0.f,0.f},{0.f,0.f,0.f,0.f},{0.f,0.f,0.f,0.f},{0.f,0.f,0.f,0.f}};
#pragma unroll
    for (int kc = 0; kc < NKC; ++kc) {
        const short8 a = load_afrag(X, (size_t)(node0 + d), K, kc, quad);
        cc[0] = __builtin_amdgcn_mfma_f32_16x16x32_bf16(a, wf[0][kc], cc[0], 0, 0, 0);
        cc[1] = __builtin_amdgcn_mfma_f32_16x16x32_bf16(a, wf[1][kc], cc[1], 0, 0, 0);
        cc[2] = __builtin_amdgcn_mfma_f32_16x16x32_bf16(a, wf[2][kc], cc[2], 0, 0, 0);
        cc[3] = __builtin_amdgcn_mfma_f32_16x16x32_bf16(a, wf[3][kc], cc[3], 0, 0, 0);
    }

#pragma unroll
    for (int ng = 0; ng < 4; ++ng) {
        const float alv = al[ng * 16 + d];
        const float arv = ar[ng * 16 + d];
        const v4f c = cc[ng];
#pragma unroll
        for (int r = 0; r < 4; ++r) {
            const int node = node0 + quad * 4 + r;
            Hout[(size_t)node * 64 + ng * 16 + d] = f2bf(c[r]);
            float vel = c[r] * alv;
            float ver = c[r] * arv;
#pragma unroll
            for (int off = 1; off < 16; off <<= 1) {
                vel += __shfl_xor(vel, off);
                ver += __shfl_xor(ver, off);
            }
            if (d == 0) {
                el[node * 4 + ng] = vel;
                er[node * 4 + ng] = ver;
            }
        }
    }
}

template <int K, typename XT>
__global__ __launch_bounds__(256) void fc_att_mfma(
    const XT* __restrict__ X, const float* __restrict__ W,
    const float* __restrict__ al, const float* __restrict__ ar,
    unsigned short* __restrict__ Hout, float* __restrict__ el,
    float* __restrict__ er, int nTiles)
{
    __shared__ __align__(16) unsigned short Wlds[64 * (K + 8)];
    fc_att_body<K, XT>(X, W, al, ar, Hout, el, er, nTiles, (int)blockIdx.x, Wlds);
}

// ---------------------------------------------------------------------------
// Bucket scatter helper: padded counter cnt16[d*16], XCD partition, col
// pre-zeroed so tail gathers hit row 0.
// ---------------------------------------------------------------------------
__device__ __forceinline__ void scat1(int d, int s, int lo, int hi,
                                      int* __restrict__ cnt16,
                                      unsigned short* __restrict__ col)
{
    if (d >= lo && d < hi) {
        const int pos = atomicAdd(&cnt16[(unsigned)d * 16], 1);
        if (pos < CAP) col[(unsigned)d * CAP + pos] = (unsigned short)s;
    }
}

// ---------------------------------------------------------------------------
// Fused layer-1 launch: blocks [0,FC_BLOCKS) run fc1 (MFMA), blocks
// [FC_BLOCKS, FC_BLOCKS+SCAT_BLOCKS) run the bucket scatter. The two are
// data-independent; fc blocks go first so both populate the CUs immediately
// and fc1's MFMA/VALU work hides under scatter's atomic/VMEM latency.
// FC_BLOCKS % 8 == 0 preserves part == blockIdx & 7 == XCD for scatter.
// ---------------------------------------------------------------------------
__global__ __launch_bounds__(256) void l1_fused_kernel(
    const float* __restrict__ X, const float* __restrict__ W,
    const float* __restrict__ al, const float* __restrict__ ar,
    unsigned short* __restrict__ Hout, float* __restrict__ el,
    float* __restrict__ er,
    const int* __restrict__ src, const int* __restrict__ dst,
    int* __restrict__ cnt16, unsigned short* __restrict__ col)
{
    __shared__ __align__(16) unsigned short Wlds[64 * (128 + 8)];
    if ((int)blockIdx.x < FC_BLOCKS) {
        fc_att_body<128, float>(X, W, al, ar, Hout, el, er,
                                N_NODES / 16, (int)blockIdx.x, Wlds);
    } else {
        const int bid = (int)blockIdx.x - FC_BLOCKS;
        const int part = bid & (NPART - 1);           // == blockIdx & 7 == XCD
        const int lo = part * PART_SZ;
        const int hi = lo + PART_SZ;
        const int tid_p = (bid >> 3) * 256 + (int)threadIdx.x;
        const int stride = (SCAT_BLOCKS / NPART) * 256;                // 131072
        const int4v* dst4 = (const int4v*)dst;
        const int4v* src4 = (const int4v*)src;
        const int NQ = N_EDGES / 4;                                    // 200000
        for (int q = tid_p; q < NQ; q += 2 * stride) {
            const int q2 = q + stride;
            const bool ok2 = q2 < NQ;
            const int4v dA = __builtin_nontemporal_load(dst4 + q);
            const int4v sA = __builtin_nontemporal_load(src4 + q);
            const int4v dB = ok2 ? __builtin_nontemporal_load(dst4 + q2) : (int4v){-1,-1,-1,-1};
            const int4v sB = ok2 ? __builtin_nontemporal_load(src4 + q2) : (int4v){0,0,0,0};
            scat1(dA[0], sA[0], lo, hi, cnt16, col);
            scat1(dA[1], sA[1], lo, hi, cnt16, col);
            scat1(dA[2], sA[2], lo, hi, cnt16, col);
            scat1(dA[3], sA[3], lo, hi, cnt16, col);
            scat1(dB[0], sB[0], lo, hi, cnt16, col);
            scat1(dB[1], sB[1], lo, hi, cnt16, col);
            scat1(dB[2], sB[2], lo, hi, cnt16, col);
            scat1(dB[3], sB[3], lo, hi, cnt16, col);
        }
    }
}

// ---------------------------------------------------------------------------
// Lane-pair agg walk: one wave = 2 nodes (halves); lane hl covers a bf16
// column pair via one u32 gather; 16-edge iters, dual 8-wide predication.
// Tail slots gather row 0 (col pre-zeroed).
// ---------------------------------------------------------------------------
__device__ __forceinline__ void agg_walk_pair(
    const unsigned short* __restrict__ colrow, int len, int len_max,
    const float* __restrict__ el, const unsigned int* __restrict__ Hf32,
    int hb, int hl, float erv_a,
    float& accL_out, float& accH_out, float& sacc_a_out)
{
    const int j_a = hl >> 2;
    const unsigned h_a = (unsigned)(hl & 3);
    const int hd = hl >> 3;
    float accL0 = 0.f, accL1 = 0.f, accH0 = 0.f, accH1 = 0.f;
    float sacc_a = 0.f;
    for (int i = 0; i < len_max; i += 16) {
        const ushort8 sv0 = __builtin_nontemporal_load((const ushort8*)(colrow + i));
        const ushort8 sv1 = __builtin_nontemporal_load((const ushort8*)(colrow + i + 8));
        const int rm = len - i;
        const unsigned sa0 = (unsigned)colrow[i + j_a];
        const unsigned sa1 = (unsigned)colrow[i + 8 + j_a];
        float x0 = el[sa0 * 4u + h_a] + erv_a;
        float x1 = el[sa1 * 4u + h_a] + erv_a;
        x0 = fmaxf(x0, 0.2f * x0);
        x1 = fmaxf(x1, 0.2f * x1);
        float a0 = __expf(x0);
        float a1 = __expf(x1);
        a0 = (j_a < rm) ? a0 : 0.f;
        a1 = (j_a + 8 < rm) ? a1 : 0.f;
        sacc_a += a0 + a1;
        unsigned uu[16];
#pragma unroll
        for (int j = 0; j < 8; ++j)
            uu[j] = Hf32[(unsigned)sv0[j] * 32u + (unsigned)hl];
#pragma unroll
        for (int j = 0; j < 8; ++j)
            uu[8 + j] = Hf32[(unsigned)sv1[j] * 32u + (unsigned)hl];
#pragma unroll
        for (int j = 0; j < 8; ++j) {
            const float aj = __shfl(a0, hb + j * 4 + hd);
            const float lo = __uint_as_float(uu[j] << 16);
            const float hi = __uint_as_float(uu[j] & 0xffff0000u);
            if (j & 1) { accL1 = fmaf(aj, lo, accL1); accH1 = fmaf(aj, hi, accH1); }
            else       { accL0 = fmaf(aj, lo, accL0); accH0 = fmaf(aj, hi, accH0); }
        }
#pragma unroll
        for (int j = 0; j < 8; ++j) {
            const float aj = __shfl(a1, hb + j * 4 + hd);
            const float lo = __uint_as_float(uu[8 + j] << 16);
            const float hi = __uint_as_float(uu[8 + j] & 0xffff0000u);
            if (j & 1) { accL1 = fmaf(aj, lo, accL1); accH1 = fmaf(aj, hi, accH1); }
            else       { accL0 = fmaf(aj, lo, accL0); accH0 = fmaf(aj, hi, accH0); }
        }
    }
    sacc_a += __shfl_xor(sacc_a, 4);
    sacc_a += __shfl_xor(sacc_a, 8);
    sacc_a += __shfl_xor(sacc_a, 16);
    sacc_a_out = sacc_a;
    accL_out = accL0 + accL1;
    accH_out = accH0 + accH1;
}

// layer-1 aggregation (2 nodes/wave): out = relu(acc/sacc + b1), packed u32 NT
__global__ __launch_bounds__(256) void agg_relu_kernel(
    const int* __restrict__ cnt16, const unsigned short* __restrict__ col,
    const float* __restrict__ el, const float* __restrict__ er,
    const unsigned int* __restrict__ Hf32, const float* __restrict__ b,
    unsigned int* __restrict__ out32, int n)
{
    const int lane = threadIdx.x & 63;
    const int wave = threadIdx.x >> 6;
    const int hl = lane & 31;
    const int hb = lane & 32;
    const int node = blockIdx.x * 8 + wave * 2 + (lane >> 5);
    if (node >= n) return;
    const int hd = hl >> 3;
    const int cg = hd * 16 + (hl & 7) * 2;
    const float erv_a = er[node * 4 + (hl & 3)];
    const int len = min(cnt16[(unsigned)node * 16], CAP);
    const int len_max = max(len, __shfl_xor(len, 32));
    float accL, accH, sacc_a;
    agg_walk_pair(col + (unsigned)node * CAP, len, len_max, el, Hf32,
                  hb, hl, erv_a, accL, accH, sacc_a);
    const float sc = __shfl(sacc_a, hb + hd);
    float vL = sc > 0.f ? accL / sc : 0.f;
    float vH = sc > 0.f ? accH / sc : 0.f;
    vL += b[cg];   vH += b[cg + 1];
    vL = vL > 0.f ? vL : 0.f;
    vH = vH > 0.f ? vH : 0.f;
    const unsigned u = (unsigned)f2bf(vL) | ((unsigned)f2bf(vH) << 16);
    __builtin_nontemporal_store(u, out32 + (size_t)node * 32 + hl);
}

// layer-2 aggregation (2 nodes/wave): head-mean (+b2) then 16-dim log-softmax
__global__ __launch_bounds__(256) void agg_final_kernel(
    const int* __restrict__ cnt16, const unsigned short* __restrict__ col,
    const float* __restrict__ el, const float* __restrict__ er,
    const unsigned int* __restrict__ Hf32, const float* __restrict__ b,
    float* __restrict__ out, int n)
{
    const int lane = threadIdx.x & 63;
    const int wave = threadIdx.x >> 6;
    const int hl = lane & 31;
    const int hb = lane & 32;
    const int node = blockIdx.x * 8 + wave * 2 + (lane >> 5);
    if (node >= n) return;
    const int hd = hl >> 3;
    const int cg = hd * 16 + (hl & 7) * 2;
    const float erv_a = er[node * 4 + (hl & 3)];
    const int len = min(cnt16[(unsigned)node * 16], CAP);
    const int len_max = max(len, __shfl_xor(len, 32));
    float accL, accH, sacc_a;
    agg_walk_pair(col + (unsigned)node * CAP, len, len_max, el, Hf32,
                  hb, hl, erv_a, accL, accH, sacc_a);
    const float sc = __shfl(sacc_a, hb + hd);
    float zL = sc > 0.f ? accL / sc : 0.f;
    float zH = sc > 0.f ? accH / sc : 0.f;
    zL += b[cg];   zH += b[cg + 1];
    zL += __shfl_xor(zL, 8);  zL += __shfl_xor(zL, 16);  zL *= 0.25f;
    zH += __shfl_xor(zH, 8);  zH += __shfl_xor(zH, 16);  zH *= 0.25f;
    float m = fmaxf(zL, zH);
    m = fmaxf(m, __shfl_xor(m, 1));
    m = fmaxf(m, __shfl_xor(m, 2));
    m = fmaxf(m, __shfl_xor(m, 4));
    float se = __expf(zL - m) + __expf(zH - m);
    se += __shfl_xor(se, 1);
    se += __shfl_xor(se, 2);
    se += __shfl_xor(se, 4);
    const float lse = __logf(se);
    if (hl < 8) {
        v2f r;
        r[0] = zL - m - lse;
        r[1] = zH - m - lse;
        __builtin_nontemporal_store(r, (v2f*)(out + (size_t)node * 16 + hl * 2));
    }
}

extern "C" void kernel_launch(void* const* d_in, const int* in_sizes, int n_in,
                              void* d_out, int out_size, void* d_ws, size_t ws_size,
                              hipStream_t stream)
{
    const float* feat = (const float*)d_in[0];
    const int*   src  = (const int*)d_in[1];
    const int*   dst  = (const int*)d_in[2];
    const float* W1   = (const float*)d_in[3];
    const float* al1  = (const float*)d_in[4];
    const float* ar1  = (const float*)d_in[5];
    const float* b1   = (const float*)d_in[6];
    const float* W2   = (const float*)d_in[7];
    const float* al2  = (const float*)d_in[8];
    const float* ar2  = (const float*)d_in[9];
    const float* b2   = (const float*)d_in[10];
    float* out = (float*)d_out;

    float* el  = (float*)d_ws;                                // [N,4]
    float* er  = el + N_NODES * 4;                            // [N,4]
    int*   cnt16 = (int*)(er + N_NODES * 4);                  // [N*16] padded
    uintptr_t p = ((uintptr_t)(cnt16 + N_NODES * 16) + 15) & ~(uintptr_t)15;
    unsigned short* col = (unsigned short*)p;                 // [N*CAP + 64]
    unsigned short* A   = col + (size_t)N_NODES * CAP + 64;   // h1 [N,64] bf16
    unsigned short* B   = A + (size_t)N_NODES * 64;           // h2 [N,64] bf16

    const int NT = N_NODES / 16;                    // 3125 tiles (exact)
    const int FB = (NT + 3) / 4;                    // 782 fc blocks (layer 2)
    const int AB2 = (N_NODES + 7) / 8;              // 6250 agg blocks

    // ---- bucket-CSR zeroing (cnt16 + col tail) ----
    (void)hipMemsetAsync(cnt16, 0, (size_t)((char*)A - (char*)cnt16), stream);

    // ---- layer 1: fc1 MFMA overlapped with bucket scatter (independent) ----
    l1_fused_kernel<<<FC_BLOCKS + SCAT_BLOCKS, 256, 0, stream>>>(
        feat, W1, al1, ar1, A, el, er, src, dst, cnt16, col);
    agg_relu_kernel<<<AB2, 256, 0, stream>>>(cnt16, col, el, er,
                                             (const unsigned int*)A, b1,
                                             (unsigned int*)B, N_NODES);

    // ---- layer 2 ----
    fc_att_mfma<64, unsigned short><<<FB, 256, 0, stream>>>(B, W2, al2, ar2, A, el, er, NT);
    agg_final_kernel<<<AB2, 256, 0, stream>>>(cnt16, col, el, er,
                                              (const unsigned int*)A, b2, out, N_NODES);
}

// Round 2
// 183.705 us; speedup vs baseline: 1.0768x; 1.0122x over previous
//
#include <hip/hip_runtime.h>
#include <math.h>

#define N_NODES 50000
#define N_EDGES 800000
#define NPART 8
#define PART_SZ ((N_NODES + NPART - 1) / NPART)   // 6250
#define CAP 64                                    // per-node bucket capacity
#define SCAT_BLOCKS 4096                          // 8 parts x 512 blocks
#define FC_BLOCKS 784                             // ceil(3125/4)=782, padded to x8

typedef __attribute__((ext_vector_type(8))) short short8;
typedef __attribute__((ext_vector_type(8))) unsigned short ushort8;
typedef __attribute__((ext_vector_type(4))) float v4f;
typedef __attribute__((ext_vector_type(2))) float v2f;
typedef __attribute__((ext_vector_type(4))) int int4v;

// ---- bf16 helpers (raw ushort storage) ----
__device__ __forceinline__ float bf2f(unsigned short h) {
    return __uint_as_float(((unsigned int)h) << 16);
}
__device__ __forceinline__ unsigned short f2bf(float f) {
    unsigned int u = __float_as_uint(f);
    u += 0x7fff + ((u >> 16) & 1);          // round-to-nearest-even
    return (unsigned short)(u >> 16);
}

// A-fragment load: lane supplies row m, k = kc*32 + quad*8 + j (j=0..7)
__device__ __forceinline__ short8 load_afrag(const float* X, size_t row, int K,
                                             int kc, int quad) {
    const float* p = X + row * K + kc * 32 + quad * 8;
    const float4 t0 = *(const float4*)p;
    const float4 t1 = *(const float4*)(p + 4);
    short8 a;
    a[0] = (short)f2bf(t0.x); a[1] = (short)f2bf(t0.y);
    a[2] = (short)f2bf(t0.z); a[3] = (short)f2bf(t0.w);
    a[4] = (short)f2bf(t1.x); a[5] = (short)f2bf(t1.y);
    a[6] = (short)f2bf(t1.z); a[7] = (short)f2bf(t1.w);
    return a;
}
__device__ __forceinline__ short8 load_afrag(const unsigned short* X, size_t row,
                                             int K, int kc, int quad) {
    return *(const short8*)(X + row * K + kc * 32 + quad * 8);  // already bf16
}

// ---------------------------------------------------------------------------
// MFMA fc + attention-coefficient body. W staged into LDS as bf16 (converted
// once by the 256-thread stage loop; waves then ds_read short8 directly).
// ---------------------------------------------------------------------------
template <int K, typename XT>
__device__ __forceinline__ void fc_att_body(
    const XT* __restrict__ X, const float* __restrict__ W,
    const float* __restrict__ al, const float* __restrict__ ar,
    unsigned short* __restrict__ Hout, float* __restrict__ el,
    float* __restrict__ er, int nTiles, int blk, unsigned short* Wlds)
{
    constexpr int KP = K + 8;                 // row pitch (u16): keeps 16B align
    constexpr int NKC = K / 32;
    const int tid = threadIdx.x;
    for (int i = tid; i < 64 * K; i += 256) {
        const int r = i / K, c = i - r * K;
        Wlds[r * KP + c] = f2bf(W[i]);
    }
    __syncthreads();

    const int lane = tid & 63;
    const int wave = tid >> 6;
    const int d = lane & 15;
    const int quad = lane >> 4;

    const int tile = blk * 4 + wave;
    if (tile >= nTiles) return;
    const int node0 = tile * 16;

    short8 wf[4][NKC];
#pragma unroll
    for (int ng = 0; ng < 4; ++ng) {
#pragma unroll
        for (int kc = 0; kc < NKC; ++kc) {
            wf[ng][kc] = *(const short8*)&Wlds[(ng * 16 + d) * KP + kc * 32 + quad * 8];
        }
    }

    v4f cc[4] = {{0.f,0.f,0.f,0.f},{0.f,0.f,0.f,0.f},{0.f,0.f,0.f,0.f},{0.f,0.f,0.f,0.f}};
#pragma unroll
    for (int kc = 0; kc < NKC; ++kc) {
        const short8 a = load_afrag(X, (size_t)(node0 + d), K, kc, quad);
        cc[0] = __builtin_amdgcn_mfma_f32_16x16x32_bf16(a, wf[0][kc], cc[0], 0, 0, 0);
        cc[1] = __builtin_amdgcn_mfma_f32_16x16x32_bf16(a, wf[1][kc], cc[1], 0, 0, 0);
        cc[2] = __builtin_amdgcn_mfma_f32_16x16x32_bf16(a, wf[2][kc], cc[2], 0, 0, 0);
        cc[3] = __builtin_amdgcn_mfma_f32_16x16x32_bf16(a, wf[3][kc], cc[3], 0, 0, 0);
    }

#pragma unroll
    for (int ng = 0; ng < 4; ++ng) {
        const float alv = al[ng * 16 + d];
        const float arv = ar[ng * 16 + d];
        const v4f c = cc[ng];
#pragma unroll
        for (int r = 0; r < 4; ++r) {
            const int node = node0 + quad * 4 + r;
            Hout[(size_t)node * 64 + ng * 16 + d] = f2bf(c[r]);
            float vel = c[r] * alv;
            float ver = c[r] * arv;
#pragma unroll
            for (int off = 1; off < 16; off <<= 1) {
                vel += __shfl_xor(vel, off);
                ver += __shfl_xor(ver, off);
            }
            if (d == 0) {
                el[node * 4 + ng] = vel;
                er[node * 4 + ng] = ver;
            }
        }
    }
}

template <int K, typename XT>
__global__ __launch_bounds__(256) void fc_att_mfma(
    const XT* __restrict__ X, const float* __restrict__ W,
    const float* __restrict__ al, const float* __restrict__ ar,
    unsigned short* __restrict__ Hout, float* __restrict__ el,
    float* __restrict__ er, int nTiles)
{
    __shared__ __align__(16) unsigned short Wlds[64 * (K + 8)];
    fc_att_body<K, XT>(X, W, al, ar, Hout, el, er, nTiles, (int)blockIdx.x, Wlds);
}

// ---------------------------------------------------------------------------
// Fused layer-1 launch: blocks [0,FC_BLOCKS) run fc1 (MFMA), blocks
// [FC_BLOCKS, FC_BLOCKS+SCAT_BLOCKS) run the bucket scatter.
// Scatter is BATCHED: phase 1 issues all 8 independent atomicAdds (results
// only collected, never consumed), then one graduated vmcnt wait, then 8
// predicated stores. The old per-scat1 atomic->wait->store chain serialized
// 8 x ~600cy of device-atomic latency per thread; batching cuts the critical
// path to ~1 x latency.
// FC_BLOCKS % 8 == 0 preserves part == blockIdx & 7 == XCD for scatter.
// ---------------------------------------------------------------------------
__global__ __launch_bounds__(256) void l1_fused_kernel(
    const float* __restrict__ X, const float* __restrict__ W,
    const float* __restrict__ al, const float* __restrict__ ar,
    unsigned short* __restrict__ Hout, float* __restrict__ el,
    float* __restrict__ er,
    const int* __restrict__ src, const int* __restrict__ dst,
    int* __restrict__ cnt16, unsigned short* __restrict__ col)
{
    __shared__ __align__(16) unsigned short Wlds[64 * (128 + 8)];
    if ((int)blockIdx.x < FC_BLOCKS) {
        fc_att_body<128, float>(X, W, al, ar, Hout, el, er,
                                N_NODES / 16, (int)blockIdx.x, Wlds);
    } else {
        const int bid = (int)blockIdx.x - FC_BLOCKS;
        const int part = bid & (NPART - 1);           // == blockIdx & 7 == XCD
        const int lo = part * PART_SZ;
        const int hi = lo + PART_SZ;
        const int tid_p = (bid >> 3) * 256 + (int)threadIdx.x;
        const int stride = (SCAT_BLOCKS / NPART) * 256;                // 131072
        const int4v* dst4 = (const int4v*)dst;
        const int4v* src4 = (const int4v*)src;
        const int NQ = N_EDGES / 4;                                    // 200000
        // tid_p < 131072 < NQ always; tid_p + stride covers the rest: the
        // grid-stride loop runs exactly once, so flatten it.
        for (int q = tid_p; q < NQ; q += 2 * stride) {
            const int q2 = q + stride;
            const bool ok2 = q2 < NQ;
            const int4v dA = __builtin_nontemporal_load(dst4 + q);
            const int4v sA = __builtin_nontemporal_load(src4 + q);
            const int4v dB = ok2 ? __builtin_nontemporal_load(dst4 + q2) : (int4v){-1,-1,-1,-1};
            const int4v sB = ok2 ? __builtin_nontemporal_load(src4 + q2) : (int4v){0,0,0,0};
            const int dd[8] = {dA[0], dA[1], dA[2], dA[3], dB[0], dB[1], dB[2], dB[3]};
            const int ss[8] = {sA[0], sA[1], sA[2], sA[3], sB[0], sB[1], sB[2], sB[3]};
            int pos[8];
#pragma unroll
            for (int j = 0; j < 8; ++j) {
                pos[j] = -1;
                if (dd[j] >= lo && dd[j] < hi)
                    pos[j] = atomicAdd(&cnt16[(unsigned)dd[j] * 16], 1);
            }
#pragma unroll
            for (int j = 0; j < 8; ++j) {
                if (pos[j] >= 0 && pos[j] < CAP)
                    col[(unsigned)dd[j] * CAP + pos[j]] = (unsigned short)ss[j];
            }
        }
    }
}

// ---------------------------------------------------------------------------
// Lane-pair agg walk: one wave = 2 nodes (halves); lane hl covers a bf16
// column pair via one u32 gather; 16-edge iters, dual 8-wide predication.
// Tail slots gather row 0 (col pre-zeroed).
// ---------------------------------------------------------------------------
__device__ __forceinline__ void agg_walk_pair(
    const unsigned short* __restrict__ colrow, int len, int len_max,
    const float* __restrict__ el, const unsigned int* __restrict__ Hf32,
    int hb, int hl, float erv_a,
    float& accL_out, float& accH_out, float& sacc_a_out)
{
    const int j_a = hl >> 2;
    const unsigned h_a = (unsigned)(hl & 3);
    const int hd = hl >> 3;
    float accL0 = 0.f, accL1 = 0.f, accH0 = 0.f, accH1 = 0.f;
    float sacc_a = 0.f;
    for (int i = 0; i < len_max; i += 16) {
        const ushort8 sv0 = __builtin_nontemporal_load((const ushort8*)(colrow + i));
        const ushort8 sv1 = __builtin_nontemporal_load((const ushort8*)(colrow + i + 8));
        const int rm = len - i;
        const unsigned sa0 = (unsigned)colrow[i + j_a];
        const unsigned sa1 = (unsigned)colrow[i + 8 + j_a];
        float x0 = el[sa0 * 4u + h_a] + erv_a;
        float x1 = el[sa1 * 4u + h_a] + erv_a;
        x0 = fmaxf(x0, 0.2f * x0);
        x1 = fmaxf(x1, 0.2f * x1);
        float a0 = __expf(x0);
        float a1 = __expf(x1);
        a0 = (j_a < rm) ? a0 : 0.f;
        a1 = (j_a + 8 < rm) ? a1 : 0.f;
        sacc_a += a0 + a1;
        unsigned uu[16];
#pragma unroll
        for (int j = 0; j < 8; ++j)
            uu[j] = Hf32[(unsigned)sv0[j] * 32u + (unsigned)hl];
#pragma unroll
        for (int j = 0; j < 8; ++j)
            uu[8 + j] = Hf32[(unsigned)sv1[j] * 32u + (unsigned)hl];
#pragma unroll
        for (int j = 0; j < 8; ++j) {
            const float aj = __shfl(a0, hb + j * 4 + hd);
            const float lo = __uint_as_float(uu[j] << 16);
            const float hi = __uint_as_float(uu[j] & 0xffff0000u);
            if (j & 1) { accL1 = fmaf(aj, lo, accL1); accH1 = fmaf(aj, hi, accH1); }
            else       { accL0 = fmaf(aj, lo, accL0); accH0 = fmaf(aj, hi, accH0); }
        }
#pragma unroll
        for (int j = 0; j < 8; ++j) {
            const float aj = __shfl(a1, hb + j * 4 + hd);
            const float lo = __uint_as_float(uu[8 + j] << 16);
            const float hi = __uint_as_float(uu[8 + j] & 0xffff0000u);
            if (j & 1) { accL1 = fmaf(aj, lo, accL1); accH1 = fmaf(aj, hi, accH1); }
            else       { accL0 = fmaf(aj, lo, accL0); accH0 = fmaf(aj, hi, accH0); }
        }
    }
    sacc_a += __shfl_xor(sacc_a, 4);
    sacc_a += __shfl_xor(sacc_a, 8);
    sacc_a += __shfl_xor(sacc_a, 16);
    sacc_a_out = sacc_a;
    accL_out = accL0 + accL1;
    accH_out = accH0 + accH1;
}

// layer-1 aggregation (2 nodes/wave): out = relu(acc/sacc + b1), packed u32 NT
__global__ __launch_bounds__(256) void agg_relu_kernel(
    const int* __restrict__ cnt16, const unsigned short* __restrict__ col,
    const float* __restrict__ el, const float* __restrict__ er,
    const unsigned int* __restrict__ Hf32, const float* __restrict__ b,
    unsigned int* __restrict__ out32, int n)
{
    const int lane = threadIdx.x & 63;
    const int wave = threadIdx.x >> 6;
    const int hl = lane & 31;
    const int hb = lane & 32;
    const int node = blockIdx.x * 8 + wave * 2 + (lane >> 5);
    if (node >= n) return;
    const int hd = hl >> 3;
    const int cg = hd * 16 + (hl & 7) * 2;
    const float erv_a = er[node * 4 + (hl & 3)];
    const int len = min(cnt16[(unsigned)node * 16], CAP);
    const int len_max = max(len, __shfl_xor(len, 32));
    float accL, accH, sacc_a;
    agg_walk_pair(col + (unsigned)node * CAP, len, len_max, el, Hf32,
                  hb, hl, erv_a, accL, accH, sacc_a);
    const float sc = __shfl(sacc_a, hb + hd);
    float vL = sc > 0.f ? accL / sc : 0.f;
    float vH = sc > 0.f ? accH / sc : 0.f;
    vL += b[cg];   vH += b[cg + 1];
    vL = vL > 0.f ? vL : 0.f;
    vH = vH > 0.f ? vH : 0.f;
    const unsigned u = (unsigned)f2bf(vL) | ((unsigned)f2bf(vH) << 16);
    __builtin_nontemporal_store(u, out32 + (size_t)node * 32 + hl);
}

// layer-2 aggregation (2 nodes/wave): head-mean (+b2) then 16-dim log-softmax
__global__ __launch_bounds__(256) void agg_final_kernel(
    const int* __restrict__ cnt16, const unsigned short* __restrict__ col,
    const float* __restrict__ el, const float* __restrict__ er,
    const unsigned int* __restrict__ Hf32, const float* __restrict__ b,
    float* __restrict__ out, int n)
{
    const int lane = threadIdx.x & 63;
    const int wave = threadIdx.x >> 6;
    const int hl = lane & 31;
    const int hb = lane & 32;
    const int node = blockIdx.x * 8 + wave * 2 + (lane >> 5);
    if (node >= n) return;
    const int hd = hl >> 3;
    const int cg = hd * 16 + (hl & 7) * 2;
    const float erv_a = er[node * 4 + (hl & 3)];
    const int len = min(cnt16[(unsigned)node * 16], CAP);
    const int len_max = max(len, __shfl_xor(len, 32));
    float accL, accH, sacc_a;
    agg_walk_pair(col + (unsigned)node * CAP, len, len_max, el, Hf32,
                  hb, hl, erv_a, accL, accH, sacc_a);
    const float sc = __shfl(sacc_a, hb + hd);
    float zL = sc > 0.f ? accL / sc : 0.f;
    float zH = sc > 0.f ? accH / sc : 0.f;
    zL += b[cg];   zH += b[cg + 1];
    zL += __shfl_xor(zL, 8);  zL += __shfl_xor(zL, 16);  zL *= 0.25f;
    zH += __shfl_xor(zH, 8);  zH += __shfl_xor(zH, 16);  zH *= 0.25f;
    float m = fmaxf(zL, zH);
    m = fmaxf(m, __shfl_xor(m, 1));
    m = fmaxf(m, __shfl_xor(m, 2));
    m = fmaxf(m, __shfl_xor(m, 4));
    float se = __expf(zL - m) + __expf(zH - m);
    se += __shfl_xor(se, 1);
    se += __shfl_xor(se, 2);
    se += __shfl_xor(se, 4);
    const float lse = __logf(se);
    if (hl < 8) {
        v2f r;
        r[0] = zL - m - lse;
        r[1] = zH - m - lse;
        __builtin_nontemporal_store(r, (v2f*)(out + (size_t)node * 16 + hl * 2));
    }
}

extern "C" void kernel_launch(void* const* d_in, const int* in_sizes, int n_in,
                              void* d_out, int out_size, void* d_ws, size_t ws_size,
                              hipStream_t stream)
{
    const float* feat = (const float*)d_in[0];
    const int*   src  = (const int*)d_in[1];
    const int*   dst  = (const int*)d_in[2];
    const float* W1   = (const float*)d_in[3];
    const float* al1  = (const float*)d_in[4];
    const float* ar1  = (const float*)d_in[5];
    const float* b1   = (const float*)d_in[6];
    const float* W2   = (const float*)d_in[7];
    const float* al2  = (const float*)d_in[8];
    const float* ar2  = (const float*)d_in[9];
    const float* b2   = (const float*)d_in[10];
    float* out = (float*)d_out;

    float* el  = (float*)d_ws;                                // [N,4]
    float* er  = el + N_NODES * 4;                            // [N,4]
    int*   cnt16 = (int*)(er + N_NODES * 4);                  // [N*16] padded
    uintptr_t p = ((uintptr_t)(cnt16 + N_NODES * 16) + 15) & ~(uintptr_t)15;
    unsigned short* col = (unsigned short*)p;                 // [N*CAP + 64]
    unsigned short* A   = col + (size_t)N_NODES * CAP + 64;   // h1 [N,64] bf16
    unsigned short* B   = A + (size_t)N_NODES * 64;           // h2 [N,64] bf16

    const int NT = N_NODES / 16;                    // 3125 tiles (exact)
    const int FB = (NT + 3) / 4;                    // 782 fc blocks (layer 2)
    const int AB2 = (N_NODES + 7) / 8;              // 6250 agg blocks

    // ---- bucket-CSR zeroing (cnt16 + col tail) ----
    (void)hipMemsetAsync(cnt16, 0, (size_t)((char*)A - (char*)cnt16), stream);

    // ---- layer 1: fc1 MFMA overlapped with bucket scatter (independent) ----
    l1_fused_kernel<<<FC_BLOCKS + SCAT_BLOCKS, 256, 0, stream>>>(
        feat, W1, al1, ar1, A, el, er, src, dst, cnt16, col);
    agg_relu_kernel<<<AB2, 256, 0, stream>>>(cnt16, col, el, er,
                                             (const unsigned int*)A, b1,
                                             (unsigned int*)B, N_NODES);

    // ---- layer 2 ----
    fc_att_mfma<64, unsigned short><<<FB, 256, 0, stream>>>(B, W2, al2, ar2, A, el, er, NT);
    agg_final_kernel<<<AB2, 256, 0, stream>>>(cnt16, col, el, er,
                                              (const unsigned int*)A, b2, out, N_NODES);
}

// Round 3
// 179.649 us; speedup vs baseline: 1.1011x; 1.0226x over previous
//
#include <hip/hip_runtime.h>
#include <math.h>

#define N_NODES 50000
#define N_EDGES 800000
#define NPART 8
#define PART_SZ ((N_NODES + NPART - 1) / NPART)   // 6250
#define CAP 64                                    // per-node bucket capacity
#define SCAT_BLOCKS 4096                          // 8 parts x 512 blocks
#define FC_BLOCKS 784                             // ceil(3125/4)=782, padded to x8

typedef __attribute__((ext_vector_type(8))) short short8;
typedef __attribute__((ext_vector_type(8))) unsigned short ushort8;
typedef __attribute__((ext_vector_type(4))) float v4f;
typedef __attribute__((ext_vector_type(2))) float v2f;
typedef __attribute__((ext_vector_type(4))) int int4v;

// ---- bf16 helpers (raw ushort storage) ----
__device__ __forceinline__ unsigned short f2bf(float f) {
    unsigned int u = __float_as_uint(f);
    u += 0x7fff + ((u >> 16) & 1);          // round-to-nearest-even
    return (unsigned short)(u >> 16);
}

// A-fragment load: lane supplies row m, k = kc*32 + quad*8 + j (j=0..7)
__device__ __forceinline__ short8 load_afrag(const float* X, size_t row, int K,
                                             int kc, int quad) {
    const float* p = X + row * K + kc * 32 + quad * 8;
    const float4 t0 = *(const float4*)p;
    const float4 t1 = *(const float4*)(p + 4);
    short8 a;
    a[0] = (short)f2bf(t0.x); a[1] = (short)f2bf(t0.y);
    a[2] = (short)f2bf(t0.z); a[3] = (short)f2bf(t0.w);
    a[4] = (short)f2bf(t1.x); a[5] = (short)f2bf(t1.y);
    a[6] = (short)f2bf(t1.z); a[7] = (short)f2bf(t1.w);
    return a;
}

// ---------------------------------------------------------------------------
// MFMA fc1 + attention-coefficient body (W staged into LDS as bf16).
// ---------------------------------------------------------------------------
template <int K, typename XT>
__device__ __forceinline__ void fc_att_body(
    const XT* __restrict__ X, const float* __restrict__ W,
    const float* __restrict__ al, const float* __restrict__ ar,
    unsigned short* __restrict__ Hout, float* __restrict__ el,
    float* __restrict__ er, int nTiles, int blk, unsigned short* Wlds)
{
    constexpr int KP = K + 8;                 // row pitch (u16): keeps 16B align
    constexpr int NKC = K / 32;
    const int tid = threadIdx.x;
    for (int i = tid; i < 64 * K; i += 256) {
        const int r = i / K, c = i - r * K;
        Wlds[r * KP + c] = f2bf(W[i]);
    }
    __syncthreads();

    const int lane = tid & 63;
    const int wave = tid >> 6;
    const int d = lane & 15;
    const int quad = lane >> 4;

    const int tile = blk * 4 + wave;
    if (tile >= nTiles) return;
    const int node0 = tile * 16;

    short8 wf[4][NKC];
#pragma unroll
    for (int ng = 0; ng < 4; ++ng) {
#pragma unroll
        for (int kc = 0; kc < NKC; ++kc) {
            wf[ng][kc] = *(const short8*)&Wlds[(ng * 16 + d) * KP + kc * 32 + quad * 8];
        }
    }

    v4f cc[4] = {{0.f,0.f,0.f,0.f},{0.f,0.f,0.f,0.f},{0.f,0.f,0.f,0.f},{0.f,0.f,0.f,0.f}};
#pragma unroll
    for (int kc = 0; kc < NKC; ++kc) {
        const short8 a = load_afrag(X, (size_t)(node0 + d), K, kc, quad);
        cc[0] = __builtin_amdgcn_mfma_f32_16x16x32_bf16(a, wf[0][kc], cc[0], 0, 0, 0);
        cc[1] = __builtin_amdgcn_mfma_f32_16x16x32_bf16(a, wf[1][kc], cc[1], 0, 0, 0);
        cc[2] = __builtin_amdgcn_mfma_f32_16x16x32_bf16(a, wf[2][kc], cc[2], 0, 0, 0);
        cc[3] = __builtin_amdgcn_mfma_f32_16x16x32_bf16(a, wf[3][kc], cc[3], 0, 0, 0);
    }

#pragma unroll
    for (int ng = 0; ng < 4; ++ng) {
        const float alv = al[ng * 16 + d];
        const float arv = ar[ng * 16 + d];
        const v4f c = cc[ng];
#pragma unroll
        for (int r = 0; r < 4; ++r) {
            const int node = node0 + quad * 4 + r;
            Hout[(size_t)node * 64 + ng * 16 + d] = f2bf(c[r]);
            float vel = c[r] * alv;
            float ver = c[r] * arv;
#pragma unroll
            for (int off = 1; off < 16; off <<= 1) {
                vel += __shfl_xor(vel, off);
                ver += __shfl_xor(ver, off);
            }
            if (d == 0) {
                el[node * 4 + ng] = vel;
                er[node * 4 + ng] = ver;
            }
        }
    }
}

// ---------------------------------------------------------------------------
// Fused layer-1 launch: blocks [0,FC_BLOCKS) run fc1 (MFMA), blocks
// [FC_BLOCKS, FC_BLOCKS+SCAT_BLOCKS) run the bucket scatter (batched atomics).
// R1 lesson: scatter is transaction-THROUGHPUT bound (~800K atomic+800K
// scattered stores); micro-restructuring is neutral. Left as-is.
// ---------------------------------------------------------------------------
__global__ __launch_bounds__(256) void l1_fused_kernel(
    const float* __restrict__ X, const float* __restrict__ W,
    const float* __restrict__ al, const float* __restrict__ ar,
    unsigned short* __restrict__ Hout, float* __restrict__ el,
    float* __restrict__ er,
    const int* __restrict__ src, const int* __restrict__ dst,
    int* __restrict__ cnt16, unsigned short* __restrict__ col)
{
    __shared__ __align__(16) unsigned short Wlds[64 * (128 + 8)];
    if ((int)blockIdx.x < FC_BLOCKS) {
        fc_att_body<128, float>(X, W, al, ar, Hout, el, er,
                                N_NODES / 16, (int)blockIdx.x, Wlds);
    } else {
        const int bid = (int)blockIdx.x - FC_BLOCKS;
        const int part = bid & (NPART - 1);           // == blockIdx & 7 == XCD
        const int lo = part * PART_SZ;
        const int hi = lo + PART_SZ;
        const int tid_p = (bid >> 3) * 256 + (int)threadIdx.x;
        const int stride = (SCAT_BLOCKS / NPART) * 256;                // 131072
        const int4v* dst4 = (const int4v*)dst;
        const int4v* src4 = (const int4v*)src;
        const int NQ = N_EDGES / 4;                                    // 200000
        for (int q = tid_p; q < NQ; q += 2 * stride) {
            const int q2 = q + stride;
            const bool ok2 = q2 < NQ;
            const int4v dA = __builtin_nontemporal_load(dst4 + q);
            const int4v sA = __builtin_nontemporal_load(src4 + q);
            const int4v dB = ok2 ? __builtin_nontemporal_load(dst4 + q2) : (int4v){-1,-1,-1,-1};
            const int4v sB = ok2 ? __builtin_nontemporal_load(src4 + q2) : (int4v){0,0,0,0};
            const int dd[8] = {dA[0], dA[1], dA[2], dA[3], dB[0], dB[1], dB[2], dB[3]};
            const int ss[8] = {sA[0], sA[1], sA[2], sA[3], sB[0], sB[1], sB[2], sB[3]};
            int pos[8];
#pragma unroll
            for (int j = 0; j < 8; ++j) {
                pos[j] = -1;
                if (dd[j] >= lo && dd[j] < hi)
                    pos[j] = atomicAdd(&cnt16[(unsigned)dd[j] * 16], 1);
            }
#pragma unroll
            for (int j = 0; j < 8; ++j) {
                if (pos[j] >= 0 && pos[j] < CAP)
                    col[(unsigned)dd[j] * CAP + pos[j]] = (unsigned short)ss[j];
            }
        }
    }
}

// ---------------------------------------------------------------------------
// One 16-edge aggregation step. ELS = element stride of the el array
// (4 for layer 1's [N,4], 16 for layer 2's cnt16-padding-aliased view).
// ---------------------------------------------------------------------------
template <int ELS>
__device__ __forceinline__ void agg_iter16(
    const unsigned short* __restrict__ colrow, int i, int rm,
    const float* __restrict__ el, const unsigned int* __restrict__ Hf32,
    int hb, int hl, int j_a, unsigned h_a, int hd, float erv_a,
    float& accL0, float& accL1, float& accH0, float& accH1, float& sacc_a)
{
    const ushort8 sv0 = __builtin_nontemporal_load((const ushort8*)(colrow + i));
    const ushort8 sv1 = __builtin_nontemporal_load((const ushort8*)(colrow + i + 8));
    const unsigned sa0 = (unsigned)colrow[i + j_a];
    const unsigned sa1 = (unsigned)colrow[i + 8 + j_a];
    float x0 = el[sa0 * ELS + h_a] + erv_a;
    float x1 = el[sa1 * ELS + h_a] + erv_a;
    x0 = fmaxf(x0, 0.2f * x0);
    x1 = fmaxf(x1, 0.2f * x1);
    float a0 = __expf(x0);
    float a1 = __expf(x1);
    a0 = (j_a < rm) ? a0 : 0.f;
    a1 = (j_a + 8 < rm) ? a1 : 0.f;
    sacc_a += a0 + a1;
    unsigned uu[16];
#pragma unroll
    for (int j = 0; j < 8; ++j)
        uu[j] = Hf32[(unsigned)sv0[j] * 32u + (unsigned)hl];
#pragma unroll
    for (int j = 0; j < 8; ++j)
        uu[8 + j] = Hf32[(unsigned)sv1[j] * 32u + (unsigned)hl];
#pragma unroll
    for (int j = 0; j < 8; ++j) {
        const float aj = __shfl(a0, hb + j * 4 + hd);
        const float lo = __uint_as_float(uu[j] << 16);
        const float hi = __uint_as_float(uu[j] & 0xffff0000u);
        if (j & 1) { accL1 = fmaf(aj, lo, accL1); accH1 = fmaf(aj, hi, accH1); }
        else       { accL0 = fmaf(aj, lo, accL0); accH0 = fmaf(aj, hi, accH0); }
    }
#pragma unroll
    for (int j = 0; j < 8; ++j) {
        const float aj = __shfl(a1, hb + j * 4 + hd);
        const float lo = __uint_as_float(uu[8 + j] << 16);
        const float hi = __uint_as_float(uu[8 + j] & 0xffff0000u);
        if (j & 1) { accL1 = fmaf(aj, lo, accL1); accH1 = fmaf(aj, hi, accH1); }
        else       { accL0 = fmaf(aj, lo, accL0); accH0 = fmaf(aj, hi, accH0); }
    }
}

// ---------------------------------------------------------------------------
// Lane-pair agg walk, iteration-0 PEELED: iter 0's loads are unconditional
// (CAP row always exists, tail zeroed, rm-predication handles len<16), which
// removes the len-load -> loop-bound -> colrow-load serial hop for the ~57%
// of nodes with len<=16.
// ---------------------------------------------------------------------------
template <int ELS>
__device__ __forceinline__ void agg_walk_pair(
    const unsigned short* __restrict__ colrow, int len, int len_max,
    const float* __restrict__ el, const unsigned int* __restrict__ Hf32,
    int hb, int hl, float erv_a,
    float& accL_out, float& accH_out, float& sacc_a_out)
{
    const int j_a = hl >> 2;
    const unsigned h_a = (unsigned)(hl & 3);
    const int hd = hl >> 3;
    float accL0 = 0.f, accL1 = 0.f, accH0 = 0.f, accH1 = 0.f;
    float sacc_a = 0.f;
    agg_iter16<ELS>(colrow, 0, len, el, Hf32, hb, hl, j_a, h_a, hd, erv_a,
                    accL0, accL1, accH0, accH1, sacc_a);
    for (int i = 16; i < len_max; i += 16)
        agg_iter16<ELS>(colrow, i, len - i, el, Hf32, hb, hl, j_a, h_a, hd,
                        erv_a, accL0, accL1, accH0, accH1, sacc_a);
    sacc_a += __shfl_xor(sacc_a, 4);
    sacc_a += __shfl_xor(sacc_a, 8);
    sacc_a += __shfl_xor(sacc_a, 16);
    sacc_a_out = sacc_a;
    accL_out = accL0 + accL1;
    accH_out = accH0 + accH1;
}

// ---------------------------------------------------------------------------
// FUSED layer-1 aggregation + fc2: one block = one 16-node tile.
// 8 waves x 2 nodes aggregate h1=relu(agg+b1) into a padded LDS tile
// ([16][33] u32 -- +1-dword pad breaks the 16-way bank conflict on the
// MFMA A-fragment ds_read_b128), barrier, then waves 0-3 each compute one
// head's 16x16 output tile (2 MFMAs) straight from LDS. Removes the 6.4MB
// h1 HBM round-trip and the fc2 launch boundary.
// h2 goes to the B buffer and el2/er2 into cnt16-row padding (bytes 16..47
// of each 64B row) -- disjoint from the h1 (A) / el1 / er1 buffers that
// other blocks are still gathering from.
// ---------------------------------------------------------------------------
__global__ __launch_bounds__(512) void agg1_fc2_fused(
    const int* __restrict__ cnt16, const unsigned short* __restrict__ col,
    const float* __restrict__ el1, const float* __restrict__ er1,
    const unsigned int* __restrict__ H1, const float* __restrict__ b1,
    const float* __restrict__ W2, const float* __restrict__ al2,
    const float* __restrict__ ar2,
    unsigned short* __restrict__ H2,
    float* __restrict__ el2, float* __restrict__ er2)   // stride-16 views
{
    __shared__ __align__(16) unsigned short W2lds[64 * 72];
    __shared__ __align__(16) unsigned int Hlds[16 * 33];

    const int tid = threadIdx.x;
    const int lane = tid & 63;
    const int wave = tid >> 6;
    const int hl = lane & 31;
    const int hb = lane & 32;
    const int nl = wave * 2 + (lane >> 5);            // 0..15 local node
    const int node = (int)blockIdx.x * 16 + nl;
    const int hd = hl >> 3;
    const int cg = hd * 16 + (hl & 7) * 2;

    // issue the latency-critical agg loads before W2 staging
    const int len = min(cnt16[(unsigned)node * 16], CAP);
    const float erv_a = er1[node * 4 + (hl & 3)];
    const float bL = b1[cg];
    const float bH = b1[cg + 1];

    // stage W2 -> bf16 LDS (4096 elems / 512 threads = 8 each)
    for (int i = tid; i < 64 * 64; i += 512) {
        const int r = i >> 6, c = i & 63;
        W2lds[r * 72 + c] = f2bf(W2[i]);
    }

    const int len_max = max(len, __shfl_xor(len, 32));
    float accL, accH, sacc_a;
    agg_walk_pair<4>(col + (unsigned)node * CAP, len, len_max, el1, H1,
                     hb, hl, erv_a, accL, accH, sacc_a);
    const float sc = __shfl(sacc_a, hb + hd);
    float vL = sc > 0.f ? accL / sc : 0.f;
    float vH = sc > 0.f ? accH / sc : 0.f;
    vL += bL;  vH += bH;
    vL = vL > 0.f ? vL : 0.f;
    vH = vH > 0.f ? vH : 0.f;
    // packed col pair (cg, cg+1) lands at u32-col cg/2 == hl: row-major tile
    Hlds[nl * 33 + hl] = (unsigned)f2bf(vL) | ((unsigned)f2bf(vH) << 16);
    __syncthreads();
    if (wave >= 4) return;

    // ---- fc2: wave ng computes out-cols ng*16..ng*16+15 of the tile ----
    const int ng = wave;
    const int d = lane & 15;
    const int quad = lane >> 4;
    const unsigned short* lds16 = (const unsigned short*)Hlds;   // pitch 66 u16
    const short8 wf0 = *(const short8*)&W2lds[(ng * 16 + d) * 72 + quad * 8];
    const short8 wf1 = *(const short8*)&W2lds[(ng * 16 + d) * 72 + 32 + quad * 8];
    const short8 a0 = *(const short8*)&lds16[(unsigned)d * 66 + quad * 8];
    const short8 a1 = *(const short8*)&lds16[(unsigned)d * 66 + 32 + quad * 8];
    v4f c0 = {0.f, 0.f, 0.f, 0.f};
    c0 = __builtin_amdgcn_mfma_f32_16x16x32_bf16(a0, wf0, c0, 0, 0, 0);
    c0 = __builtin_amdgcn_mfma_f32_16x16x32_bf16(a1, wf1, c0, 0, 0, 0);

    const float alv = al2[ng * 16 + d];
    const float arv = ar2[ng * 16 + d];
#pragma unroll
    for (int r = 0; r < 4; ++r) {
        const int node2 = (int)blockIdx.x * 16 + quad * 4 + r;
        H2[(size_t)node2 * 64 + ng * 16 + d] = f2bf(c0[r]);
        float vel = c0[r] * alv;
        float ver = c0[r] * arv;
#pragma unroll
        for (int off = 1; off < 16; off <<= 1) {
            vel += __shfl_xor(vel, off);
            ver += __shfl_xor(ver, off);
        }
        if (d == 0) {
            el2[node2 * 16 + ng] = vel;
            er2[node2 * 16 + ng] = ver;
        }
    }
}

// ---------------------------------------------------------------------------
// layer-2 aggregation (2 nodes/wave): head-mean (+b2) then 16-dim log-softmax.
// el2/er2 are the stride-16 cnt16-padding views.
// ---------------------------------------------------------------------------
__global__ __launch_bounds__(256) void agg_final_kernel(
    const int* __restrict__ cnt16, const unsigned short* __restrict__ col,
    const float* __restrict__ el2, const float* __restrict__ er2,
    const unsigned int* __restrict__ Hf32, const float* __restrict__ b,
    float* __restrict__ out, int n)
{
    const int lane = threadIdx.x & 63;
    const int wave = threadIdx.x >> 6;
    const int hl = lane & 31;
    const int hb = lane & 32;
    const int node = blockIdx.x * 8 + wave * 2 + (lane >> 5);
    if (node >= n) return;
    const int hd = hl >> 3;
    const int cg = hd * 16 + (hl & 7) * 2;
    const float erv_a = er2[node * 16 + (hl & 3)];
    const float bL = b[cg];
    const float bH = b[cg + 1];
    const int len = min(cnt16[(unsigned)node * 16], CAP);
    const int len_max = max(len, __shfl_xor(len, 32));
    float accL, accH, sacc_a;
    agg_walk_pair<16>(col + (unsigned)node * CAP, len, len_max, el2, Hf32,
                      hb, hl, erv_a, accL, accH, sacc_a);
    const float sc = __shfl(sacc_a, hb + hd);
    float zL = sc > 0.f ? accL / sc : 0.f;
    float zH = sc > 0.f ? accH / sc : 0.f;
    zL += bL;   zH += bH;
    zL += __shfl_xor(zL, 8);  zL += __shfl_xor(zL, 16);  zL *= 0.25f;
    zH += __shfl_xor(zH, 8);  zH += __shfl_xor(zH, 16);  zH *= 0.25f;
    float m = fmaxf(zL, zH);
    m = fmaxf(m, __shfl_xor(m, 1));
    m = fmaxf(m, __shfl_xor(m, 2));
    m = fmaxf(m, __shfl_xor(m, 4));
    float se = __expf(zL - m) + __expf(zH - m);
    se += __shfl_xor(se, 1);
    se += __shfl_xor(se, 2);
    se += __shfl_xor(se, 4);
    const float lse = __logf(se);
    if (hl < 8) {
        v2f r;
        r[0] = zL - m - lse;
        r[1] = zH - m - lse;
        __builtin_nontemporal_store(r, (v2f*)(out + (size_t)node * 16 + hl * 2));
    }
}

extern "C" void kernel_launch(void* const* d_in, const int* in_sizes, int n_in,
                              void* d_out, int out_size, void* d_ws, size_t ws_size,
                              hipStream_t stream)
{
    const float* feat = (const float*)d_in[0];
    const int*   src  = (const int*)d_in[1];
    const int*   dst  = (const int*)d_in[2];
    const float* W1   = (const float*)d_in[3];
    const float* al1  = (const float*)d_in[4];
    const float* ar1  = (const float*)d_in[5];
    const float* b1   = (const float*)d_in[6];
    const float* W2   = (const float*)d_in[7];
    const float* al2  = (const float*)d_in[8];
    const float* ar2  = (const float*)d_in[9];
    const float* b2   = (const float*)d_in[10];
    float* out = (float*)d_out;

    float* el1 = (float*)d_ws;                                // [N,4]
    float* er1 = el1 + N_NODES * 4;                           // [N,4]
    int*   cnt16 = (int*)(er1 + N_NODES * 4);                 // [N*16] padded
    uintptr_t p = ((uintptr_t)(cnt16 + N_NODES * 16) + 15) & ~(uintptr_t)15;
    unsigned short* col = (unsigned short*)p;                 // [N*CAP + 64]
    unsigned short* A   = col + (size_t)N_NODES * CAP + 64;   // h1 [N,64] bf16
    unsigned short* B   = A + (size_t)N_NODES * 64;           // h2 [N,64] bf16
    // layer-2 attention coeffs live in the cnt16 row padding (bytes 16..47
    // of each 64B row): zero workspace growth, disjoint from the counter.
    float* el2 = (float*)cnt16 + 4;                           // stride 16
    float* er2 = (float*)cnt16 + 8;                           // stride 16

    const int AB2 = (N_NODES + 7) / 8;              // 6250 agg blocks
    const int TILES = N_NODES / 16;                 // 3125 (exact)

    // ---- bucket-CSR zeroing (cnt16 rows incl. el2/er2 pads + col tail) ----
    (void)hipMemsetAsync(cnt16, 0, (size_t)((char*)A - (char*)cnt16), stream);

    // ---- layer 1: fc1 MFMA overlapped with bucket scatter (independent) ----
    l1_fused_kernel<<<FC_BLOCKS + SCAT_BLOCKS, 256, 0, stream>>>(
        feat, W1, al1, ar1, A, el1, er1, src, dst, cnt16, col);

    // ---- agg1 + fc2 fused (h1 never leaves the block) ----
    agg1_fc2_fused<<<TILES, 512, 0, stream>>>(
        cnt16, col, el1, er1, (const unsigned int*)A, b1,
        W2, al2, ar2, B, el2, er2);

    // ---- layer 2 aggregation + log-softmax ----
    agg_final_kernel<<<AB2, 256, 0, stream>>>(cnt16, col, el2, er2,
                                              (const unsigned int*)B, b2,
                                              out, N_NODES);
}